// Round 6
// baseline (103.377 us; speedup 1.0000x reference)
//
#include <hip/hip_runtime.h>
#include <math.h>

// AtomQueryFieldNet: NQ=4096, NA=512, pair MLP 18->64->64->32->1, cutoff mask,
// per-query 3-vector reduction, 3->64->3 head.
//
// R20: pair-packed table — ONE 8B gather per (query,atom).
//  - R19 post-mortem: dispatch/staging cleanup gained ~0.5us -> field kernel's
//    scattered gathers are the dominant residual (8 iters x 2 dword x 64 lanes
//    = 1024 unique cache lines/wave, request-bound ~6-7us).
//  - Table stored as overlapping pairs tabP[a][i] = (G_i, G_{i+1}) float2,
//    8B-aligned -> field does one global_load_dwordx2 per pair lookup
//    (halves line count). lerp = p.x + frac*(p.y-p.x).
//  - Sample re-grid: NS-1 = 504 = 63*8. Wave w of atom a computes 64 samples
//    at indices 63w..63w+63 (spans overlap by 1) and writes pair entries
//    63w..63w+62 — every (s_i, s_{i+1}) is intra-wave. After the cross-quad
//    shfl reduction every lane holds s for its col; lane L's own (cc,u) =
//    (bit5, bit4) value IS sample L of the span (static 2-bit select), and
//    s_{i+1} = __shfl_down(s,1). Overlap samples recomputed bit-identically
//    by adjacent waves.
//  - d_i = i*6/504 (step 84/"inverse" exact in fp). Error vs 6/511 grid:
//    x1.03 lerp error — negligible; table values via the identical f16 MLP.
//  - Keeps R19: fused in-block repack (global->LDS f32->f16, same cvt chain),
//    grid 1024 = one 4-blocks/CU round, #pragma unroll 1 + opaque wb keeps
//    frag ds_reads transient, dist via EXACT reference __fadd_rn/__fmul_rn/
//    sqrtf sequence (cutoff boundary bitwise-stable).
//  - ws: [0, 2MB) pair table (512 atoms x 512-entry stride x 8B).

typedef _Float16 f16x4 __attribute__((ext_vector_type(4)));
typedef _Float16 f16x2 __attribute__((ext_vector_type(2)));
typedef float    f32x4 __attribute__((ext_vector_type(4)));

#define MFMA16(A,B,C) __builtin_amdgcn_mfma_f32_16x16x16f16(A,B,C,0,0,0)

__device__ __forceinline__ float exp2_fast(float x) {
    float r;
    asm("v_exp_f32 %0, %1" : "=v"(r) : "v"(x));
    return r;
}

__device__ __forceinline__ f16x4 relu_cvt(f32x4 c) {
    return f16x4{(_Float16)fmaxf(c[0],0.f), (_Float16)fmaxf(c[1],0.f),
                 (_Float16)fmaxf(c[2],0.f), (_Float16)fmaxf(c[3],0.f)};
}

// ---- tabgen: pair table (G_a(d_i), G_a(d_{i+1})), d_i = i*6/504 ----
// Fused in-block repack: wlds frag layout (32 f16x4 frags x 64 lanes):
//   f 0..7  L1 (kc*4+mt, kc<2)   elem j: W1'[k=kc*16+quad*4+j][mt*16+col]
//   f 8..23 L2 (kc*4+mt, kc<4)           W2 [k][mt*16+col]
//   f 24..31 L3 (kc*2+mt, kc<4)          W3 [k][mt*16+col]
// W1' ROW-PERMUTED: k 0..15 = rbf rows (orig 2..17), k16=f0(row0),
// k17=f1(row1), k18=b1, k>=19 zero. biaslds[128] = {b2[64], b3[32], W4[32]}.
// Grid 1024 x 256: wave wc = bid*4+wave -> atom wc>>3, span start (wc&7)*63.
__global__ __launch_bounds__(256, 4) void tabgen_kernel(
    const float* __restrict__ atom_feat,  // (512,2)
    const float* __restrict__ W1, const float* __restrict__ b1,
    const float* __restrict__ W2, const float* __restrict__ b2,
    const float* __restrict__ W3, const float* __restrict__ b3,
    const float* __restrict__ W4, const float* __restrict__ b4,
    float2* __restrict__ tabP)            // (512, 512) pair entries, 504 used
{
    __shared__ __align__(16) f16x4 wlds[2048];     // 16KB frags
    __shared__ __align__(16) float biaslds[128];   // 512B biases

    const int tid  = threadIdx.x;
    const int wave = __builtin_amdgcn_readfirstlane(tid >> 6);
    const int lane = tid & 63;
    const int col  = lane & 15;
    const int quad = lane >> 4;

    // ---- fused repack: global -> LDS (8 frag slots per thread) ----
    #pragma unroll
    for (int sidx = 0; sidx < 8; ++sidx) {
        const int s  = tid + sidx*256;     // slot = frag*64 + lane
        const int b  = s >> 6;
        const int sl = s & 63;
        const int scol = sl & 15, squad = sl >> 4;
        f16x4 v;
        #pragma unroll
        for (int j = 0; j < 4; ++j) {
            float x;
            if (b < 8) {
                const int kc = b >> 2, mt = b & 3;
                const int k = kc*16 + squad*4 + j;
                if (k < 16)       x = W1[(k+2)*64 + mt*16 + scol];  // rbf rows
                else if (k == 16) x = W1[        mt*16 + scol];     // f0
                else if (k == 17) x = W1[ 64   + mt*16 + scol];     // f1
                else if (k == 18) x = b1[        mt*16 + scol];     // bias slot
                else              x = 0.0f;
            } else if (b < 24) {
                const int idx = b - 8, kc = idx >> 2, mt = idx & 3;
                const int k = kc*16 + squad*4 + j;
                x = W2[k*64 + mt*16 + scol];
            } else {
                const int idx = b - 24, kc = idx >> 1, mt = idx & 1;
                const int k = kc*16 + squad*4 + j;
                x = W3[k*32 + mt*16 + scol];
            }
            v[j] = (_Float16)x;
        }
        wlds[s] = v;
    }
    if (tid < 128) {
        float x;
        if (tid < 64)       x = b2[tid];
        else if (tid < 96)  x = b3[tid - 64];
        else                x = W4[tid - 96];
        biaslds[tid] = x;
    }
    __syncthreads();

    const int wc  = blockIdx.x * 4 + wave;  // 0..4095
    const int a   = wc >> 3;                // atom (8 waves per atom)
    const int s0w = (wc & 7) * 63;          // span start (overlap-by-1 spans)
    const float f0  = atom_feat[a*2+0];     // wave-uniform
    const float f1  = atom_feat[a*2+1];
    const float b4v = b4[0];

    // centers linspace(0,6,16): exp(-10 t^2) = 2^(-(s*t)^2),
    // s = sqrt(10*log2 e) = 3.7982831, step 0.4*s = 1.5193132.
    const float cbase = 1.5193132f * (float)(quad*4);

    float s00, s01, s10, s11;   // s[cc][u]: sample s0w + cc*32 + u*16 + col

    #pragma unroll 1
    for (int cc = 0; cc < 2; ++cc) {
        const int i0 = s0w + cc*32;

        // opaque zero: keeps frag/bias ds_reads transient per chunk
        int wb = 0;
        asm volatile("" : "+v"(wb));
        const float4* bias4 = (const float4*)biaslds;

        f16x4 xa0[2], xa1[2];
        #pragma unroll
        for (int u = 0; u < 2; ++u) {
            const int   idx  = i0 + u*16 + col;
            const float dist = (float)idx * (6.0f/504.0f);
            const float base = __fmul_rn(dist, 3.7982831f) - cbase;
            #pragma unroll
            for (int j = 0; j < 4; ++j) {
                const float t = base - 1.5193132f * (float)j;
                xa0[u][j] = (_Float16)exp2_fast(t * -t);
            }
            const bool q0 = (quad == 0);
            xa1[u] = f16x4{q0 ? (_Float16)f0 : (_Float16)0.f,
                           q0 ? (_Float16)f1 : (_Float16)0.f,
                           (_Float16)(q0 ? 1.f : 0.f),
                           (_Float16)0.f};
        }

        // ---- L1 ----
        f16x4 t1[2][4];
        #pragma unroll
        for (int kc = 0; kc < 2; ++kc)
            #pragma unroll
            for (int mt = 0; mt < 4; ++mt)
                t1[kc][mt] = wlds[wb + (kc*4 + mt)*64 + lane];
        f16x4 a2[2][4];
        #pragma unroll
        for (int u = 0; u < 2; ++u)
            #pragma unroll
            for (int mt = 0; mt < 4; ++mt) {
                f32x4 cc2 = {0.f, 0.f, 0.f, 0.f};
                cc2 = MFMA16(t1[0][mt], xa0[u], cc2);
                cc2 = MFMA16(t1[1][mt], xa1[u], cc2);
                a2[u][mt] = relu_cvt(cc2);
            }

        // ---- L2 ----
        f16x4 t2[4][4];
        #pragma unroll
        for (int kc = 0; kc < 4; ++kc)
            #pragma unroll
            for (int mt = 0; mt < 4; ++mt)
                t2[kc][mt] = wlds[wb + (8 + kc*4 + mt)*64 + lane];
        float4 b2v[4];
        #pragma unroll
        for (int mt = 0; mt < 4; ++mt) b2v[mt] = bias4[wb + mt*4 + quad];
        f16x4 a3[2][4];
        #pragma unroll
        for (int u = 0; u < 2; ++u)
            #pragma unroll
            for (int mt = 0; mt < 4; ++mt) {
                f32x4 cc2 = {b2v[mt].x, b2v[mt].y, b2v[mt].z, b2v[mt].w};
                #pragma unroll
                for (int kc = 0; kc < 4; ++kc)
                    cc2 = MFMA16(t2[kc][mt], a2[u][kc], cc2);
                a3[u][mt] = relu_cvt(cc2);
            }

        // ---- L3 + L4 partial + quad-reduce ----
        f16x4 t3[4][2];
        #pragma unroll
        for (int kc = 0; kc < 4; ++kc)
            #pragma unroll
            for (int mt = 0; mt < 2; ++mt)
                t3[kc][mt] = wlds[wb + (24 + kc*2 + mt)*64 + lane];
        float4 b3v[2], w4v[2];
        #pragma unroll
        for (int mt = 0; mt < 2; ++mt) {
            b3v[mt] = bias4[wb + 16 + mt*4 + quad];
            w4v[mt] = bias4[wb + 24 + mt*4 + quad];
        }
        float su[2];
        #pragma unroll
        for (int u = 0; u < 2; ++u) {
            float s = 0.f;
            #pragma unroll
            for (int mt = 0; mt < 2; ++mt) {
                f32x4 cc2 = {b3v[mt].x, b3v[mt].y, b3v[mt].z, b3v[mt].w};
                #pragma unroll
                for (int kc = 0; kc < 4; ++kc)
                    cc2 = MFMA16(t3[kc][mt], a3[u][kc], cc2);
                const float* wv = &w4v[mt].x;
                #pragma unroll
                for (int rr = 0; rr < 4; ++rr)
                    s = fmaf(fmaxf(cc2[rr], 0.f), wv[rr], s);
            }
            s += __shfl_xor(s, 16);   // sum quad partials -> all lanes hold
            s += __shfl_xor(s, 32);   // full s for sample (cc,u,col)
            s += b4v;
            su[u] = s;                // u compile-time (unrolled) -> register
        }
        if (cc == 0) { s00 = su[0]; s01 = su[1]; }
        else         { s10 = su[0]; s11 = su[1]; }
    }

    // ---- assemble pairs: lane L holds sample s0w+L via static 2-bit select
    const float sa = (lane & 32) ? ((lane & 16) ? s11 : s10)
                                 : ((lane & 16) ? s01 : s00);
    const float sn = __shfl_down(sa, 1);
    if (lane < 63)
        tabP[a*512 + s0w + lane] = make_float2(sa, sn);
}

// ---- field: dense 512-atom sweep, ONE float2 gather + lerp per pair ----
__global__ __launch_bounds__(256, 4) void field_kernel(
    const float* __restrict__ atom_pos,   // (512,3)
    const float* __restrict__ query_pos,  // (4096,3)
    const float* __restrict__ W5, const float* __restrict__ b5,  // (3,64),(64)
    const float* __restrict__ W6, const float* __restrict__ b6,  // (64,3),(3)
    const float2* __restrict__ tabP,      // (512, 512) pair entries
    float* __restrict__ out)              // (4096,3)
{
    __shared__ float px[512], py[512], pz[512];   // 6KB SoA, conflict-free

    const int tid  = threadIdx.x;
    const int wave = __builtin_amdgcn_readfirstlane(tid >> 6);
    const int lane = tid & 63;
    const int q    = blockIdx.x * 4 + wave;   // grid=1024 -> q < 4096

    #pragma unroll
    for (int i = tid; i < 512; i += 256) {
        px[i] = atom_pos[i*3+0];
        py[i] = atom_pos[i*3+1];
        pz[i] = atom_pos[i*3+2];
    }
    __syncthreads();

    const float qx = query_pos[q*3+0];
    const float qy = query_pos[q*3+1];
    const float qz = query_pos[q*3+2];

    float acc0 = 0.f, acc1 = 0.f, acc2 = 0.f;
    #pragma unroll
    for (int it = 0; it < 8; ++it) {
        const int a = it*64 + lane;
        const float rx = qx - px[a];
        const float ry = qy - py[a];
        const float rz = qz - pz[a];
        // EXACT reference dist sequence (mask boundary bitwise-stable)
        const float ex = __fadd_rn(rx, 1e-12f);
        const float ey = __fadd_rn(ry, 1e-12f);
        const float ez = __fadd_rn(rz, 1e-12f);
        const float dd = __fadd_rn(__fadd_rn(__fmul_rn(ex,ex), __fmul_rn(ey,ey)),
                                   __fmul_rn(ez,ez));
        const float dist = sqrtf(dd);
        const bool  in   = dist <= 6.0f;
        const float t  = __fmul_rn(dist, 84.0f);   // (NS-1)/6 = 504/6, exact
        int   i  = (int)t;
        i = i < 503 ? i : 503;
        const float frac = t - (float)i;
        const float2 p = tabP[a*512 + i];          // one 8B-aligned gather
        const float sv = fmaf(frac, p.y - p.x, p.x);
        const float inv = __builtin_amdgcn_rcpf(dist + 1e-12f);
        const float wm  = in ? sv * inv : 0.f;
        acc0 = fmaf(wm, rx, acc0);
        acc1 = fmaf(wm, ry, acc1);
        acc2 = fmaf(wm, rz, acc2);
    }

    // ---- 64-lane butterfly (each atom counted exactly once) ----
    #pragma unroll
    for (int o = 1; o < 64; o <<= 1) {
        acc0 += __shfl_xor(acc0, o);
        acc1 += __shfl_xor(acc1, o);
        acc2 += __shfl_xor(acc2, o);
    }

    // ---- head: 3 -> 64 -> 3, per wave (lane = hidden unit) ----
    int hz = 0;
    asm volatile("" : "+v"(hz));   // keep head loads after the loop
    const float w5x = W5[hz + lane];
    const float w5y = W5[hz + 64 + lane];
    const float w5z = W5[hz + 128 + lane];
    const float b5v = b5[hz + lane];
    float th = fmaf(acc0, w5x, fmaf(acc1, w5y, fmaf(acc2, w5z, b5v)));
    th = fmaxf(th, 0.f);
    float o0 = th * W6[hz + lane*3+0];
    float o1 = th * W6[hz + lane*3+1];
    float o2 = th * W6[hz + lane*3+2];
    #pragma unroll
    for (int o = 1; o < 64; o <<= 1) {
        o0 += __shfl_xor(o0, o);
        o1 += __shfl_xor(o1, o);
        o2 += __shfl_xor(o2, o);
    }
    if (lane == 0) {
        out[q*3+0] = o0 + b6[0];
        out[q*3+1] = o1 + b6[1];
        out[q*3+2] = o2 + b6[2];
    }
}

extern "C" void kernel_launch(void* const* d_in, const int* in_sizes, int n_in,
                              void* d_out, int out_size, void* d_ws, size_t ws_size,
                              hipStream_t stream) {
    const float* atom_pos  = (const float*)d_in[0];
    const float* atom_feat = (const float*)d_in[1];
    const float* query_pos = (const float*)d_in[2];
    const float* W1 = (const float*)d_in[3];  const float* b1 = (const float*)d_in[4];
    const float* W2 = (const float*)d_in[5];  const float* b2 = (const float*)d_in[6];
    const float* W3 = (const float*)d_in[7];  const float* b3 = (const float*)d_in[8];
    const float* W4 = (const float*)d_in[9];  const float* b4 = (const float*)d_in[10];
    const float* W5 = (const float*)d_in[11]; const float* b5 = (const float*)d_in[12];
    const float* W6 = (const float*)d_in[13]; const float* b6 = (const float*)d_in[14];
    float* out = (float*)d_out;
    float2* tabP = (float2*)d_ws;   // 512 x 512 pairs = 2MB

    hipLaunchKernelGGL(tabgen_kernel, dim3(1024), dim3(256), 0, stream,
                       atom_feat, W1, b1, W2, b2, W3, b3, W4, b4, tabP);
    hipLaunchKernelGGL(field_kernel, dim3(1024), dim3(256), 0, stream,
                       atom_pos, query_pos, W5, b5, W6, b6,
                       tabP, out);
}

// Round 8
// 98.729 us; speedup vs baseline: 1.0471x; 1.0471x over previous
//
#include <hip/hip_runtime.h>
#include <math.h>

// AtomQueryFieldNet: NQ=4096, NA=512, pair MLP 18->64->64->32->1, cutoff mask,
// per-query 3-vector reduction, 3->64->3 head.
//
// R22: revert to R19 two-dispatch structure (R21 cooperative launch never ran
// under graph capture -> output stayed zero). One safe delta vs R19:
//  - field kernel predicates the table gather under the cutoff test: exec
//    mask suppresses VMEM requests for out-of-range lanes (~2/3 of atoms),
//    cutting gather line traffic ~3x. Masked lanes produced wm=0 anyway ->
//    values identical.
//  - tabgen is BYTE-IDENTICAL to R19 -> same table bits -> same output bits
//    (absmax 0.015625, f16-MLP floor).
//  - Table identity (R18): pair scalar s(q,a)=MLP(f0_a,f1_a,rbf(d)) depends
//    only on (atom,d) -> tabulate G_a(d), NS=512 over [0,6]; field =
//    dist + 2-pt lerp + s/d + 3 fmaf per pair, dense over 512 atoms.
//  - dist uses the EXACT reference __fadd_rn/__fmul_rn/sqrtf sequence ->
//    cutoff boundary bitwise-stable.
//  - ws: [0, 1MB) scalar f32 table.

typedef _Float16 f16x4 __attribute__((ext_vector_type(4)));
typedef _Float16 f16x2 __attribute__((ext_vector_type(2)));
typedef float    f32x4 __attribute__((ext_vector_type(4)));

#define NS 512        // distance samples per atom over [0,6]

#define MFMA16(A,B,C) __builtin_amdgcn_mfma_f32_16x16x16f16(A,B,C,0,0,0)

__device__ __forceinline__ float exp2_fast(float x) {
    float r;
    asm("v_exp_f32 %0, %1" : "=v"(r) : "v"(x));
    return r;
}

__device__ __forceinline__ f16x4 relu_cvt(f32x4 c) {
    return f16x4{(_Float16)fmaxf(c[0],0.f), (_Float16)fmaxf(c[1],0.f),
                 (_Float16)fmaxf(c[2],0.f), (_Float16)fmaxf(c[3],0.f)};
}

// ---- tabgen: G_a(d_i), a in [0,512), i in [0,NS), d_i = i*6/511 ----
// Fused in-block repack: wlds frag layout (32 f16x4 frags x 64 lanes):
//   f 0..7  L1 (kc*4+mt, kc<2)   elem j: W1'[k=kc*16+quad*4+j][mt*16+col]
//   f 8..23 L2 (kc*4+mt, kc<4)           W2 [k][mt*16+col]
//   f 24..31 L3 (kc*2+mt, kc<4)          W3 [k][mt*16+col]
// W1' ROW-PERMUTED: k 0..15 = rbf rows (orig 2..17), k16=f0(row0),
// k17=f1(row1), k18=b1, k>=19 zero. biaslds[128] = {b2[64], b3[32], W4[32]}.
// Grid 1024 x 256: wave wc = bid*4+wave owns atom wc>>3, samples
// [(wc&7)*64, +64) as 2 chunks of 32.
__global__ __launch_bounds__(256, 4) void tabgen_kernel(
    const float* __restrict__ atom_feat,  // (512,2)
    const float* __restrict__ W1, const float* __restrict__ b1,
    const float* __restrict__ W2, const float* __restrict__ b2,
    const float* __restrict__ W3, const float* __restrict__ b3,
    const float* __restrict__ W4, const float* __restrict__ b4,
    float* __restrict__ tab)              // (512, NS)
{
    __shared__ __align__(16) f16x4 wlds[2048];     // 16KB frags
    __shared__ __align__(16) float biaslds[128];   // 512B biases

    const int tid  = threadIdx.x;
    const int wave = __builtin_amdgcn_readfirstlane(tid >> 6);
    const int lane = tid & 63;
    const int col  = lane & 15;
    const int quad = lane >> 4;

    // ---- fused repack: global -> LDS (8 frag slots per thread) ----
    #pragma unroll
    for (int sidx = 0; sidx < 8; ++sidx) {
        const int s  = tid + sidx*256;     // slot = frag*64 + lane
        const int b  = s >> 6;
        const int sl = s & 63;
        const int scol = sl & 15, squad = sl >> 4;
        f16x4 v;
        #pragma unroll
        for (int j = 0; j < 4; ++j) {
            float x;
            if (b < 8) {
                const int kc = b >> 2, mt = b & 3;
                const int k = kc*16 + squad*4 + j;
                if (k < 16)       x = W1[(k+2)*64 + mt*16 + scol];  // rbf rows
                else if (k == 16) x = W1[        mt*16 + scol];     // f0
                else if (k == 17) x = W1[ 64   + mt*16 + scol];     // f1
                else if (k == 18) x = b1[        mt*16 + scol];     // bias slot
                else              x = 0.0f;
            } else if (b < 24) {
                const int idx = b - 8, kc = idx >> 2, mt = idx & 3;
                const int k = kc*16 + squad*4 + j;
                x = W2[k*64 + mt*16 + scol];
            } else {
                const int idx = b - 24, kc = idx >> 1, mt = idx & 1;
                const int k = kc*16 + squad*4 + j;
                x = W3[k*32 + mt*16 + scol];
            }
            v[j] = (_Float16)x;
        }
        wlds[s] = v;
    }
    if (tid < 128) {
        float x;
        if (tid < 64)       x = b2[tid];
        else if (tid < 96)  x = b3[tid - 64];
        else                x = W4[tid - 96];
        biaslds[tid] = x;
    }
    __syncthreads();

    const int wc     = blockIdx.x * 4 + wave;  // 0..4095
    const int a      = wc >> 3;                // atom (8 waves per atom)
    const int i0base = (wc & 7) * 64;          // 64-sample span, 2 chunks
    const float f0  = atom_feat[a*2+0];        // wave-uniform
    const float f1  = atom_feat[a*2+1];
    const float b4v = b4[0];

    // centers linspace(0,6,16): exp(-10 t^2) = 2^(-(s*t)^2),
    // s = sqrt(10*log2 e) = 3.7982831, step 0.4*s = 1.5193132.
    const float cbase = 1.5193132f * (float)(quad*4);

    #pragma unroll 1
    for (int cc = 0; cc < 2; ++cc) {
        const int i0 = i0base + cc*32;

        // opaque zero: keeps frag/bias ds_reads transient per chunk
        int wb = 0;
        asm volatile("" : "+v"(wb));
        const float4* bias4 = (const float4*)biaslds;

        f16x4 xa0[2], xa1[2];
        #pragma unroll
        for (int u = 0; u < 2; ++u) {
            const int   idx  = i0 + u*16 + col;
            const float dist = (float)idx * (6.0f/511.0f);
            const float base = __fmul_rn(dist, 3.7982831f) - cbase;
            #pragma unroll
            for (int j = 0; j < 4; ++j) {
                const float t = base - 1.5193132f * (float)j;
                xa0[u][j] = (_Float16)exp2_fast(t * -t);
            }
            const bool q0 = (quad == 0);
            xa1[u] = f16x4{q0 ? (_Float16)f0 : (_Float16)0.f,
                           q0 ? (_Float16)f1 : (_Float16)0.f,
                           (_Float16)(q0 ? 1.f : 0.f),
                           (_Float16)0.f};
        }

        // ---- L1 ----
        f16x4 t1[2][4];
        #pragma unroll
        for (int kc = 0; kc < 2; ++kc)
            #pragma unroll
            for (int mt = 0; mt < 4; ++mt)
                t1[kc][mt] = wlds[wb + (kc*4 + mt)*64 + lane];
        f16x4 a2[2][4];
        #pragma unroll
        for (int u = 0; u < 2; ++u)
            #pragma unroll
            for (int mt = 0; mt < 4; ++mt) {
                f32x4 cc2 = {0.f, 0.f, 0.f, 0.f};
                cc2 = MFMA16(t1[0][mt], xa0[u], cc2);
                cc2 = MFMA16(t1[1][mt], xa1[u], cc2);
                a2[u][mt] = relu_cvt(cc2);
            }

        // ---- L2 ----
        f16x4 t2[4][4];
        #pragma unroll
        for (int kc = 0; kc < 4; ++kc)
            #pragma unroll
            for (int mt = 0; mt < 4; ++mt)
                t2[kc][mt] = wlds[wb + (8 + kc*4 + mt)*64 + lane];
        float4 b2v[4];
        #pragma unroll
        for (int mt = 0; mt < 4; ++mt) b2v[mt] = bias4[wb + mt*4 + quad];
        f16x4 a3[2][4];
        #pragma unroll
        for (int u = 0; u < 2; ++u)
            #pragma unroll
            for (int mt = 0; mt < 4; ++mt) {
                f32x4 cc2 = {b2v[mt].x, b2v[mt].y, b2v[mt].z, b2v[mt].w};
                #pragma unroll
                for (int kc = 0; kc < 4; ++kc)
                    cc2 = MFMA16(t2[kc][mt], a2[u][kc], cc2);
                a3[u][mt] = relu_cvt(cc2);
            }

        // ---- L3 + L4 partial + quad-reduce -> store ----
        f16x4 t3[4][2];
        #pragma unroll
        for (int kc = 0; kc < 4; ++kc)
            #pragma unroll
            for (int mt = 0; mt < 2; ++mt)
                t3[kc][mt] = wlds[wb + (24 + kc*2 + mt)*64 + lane];
        float4 b3v[2], w4v[2];
        #pragma unroll
        for (int mt = 0; mt < 2; ++mt) {
            b3v[mt] = bias4[wb + 16 + mt*4 + quad];
            w4v[mt] = bias4[wb + 24 + mt*4 + quad];
        }
        #pragma unroll
        for (int u = 0; u < 2; ++u) {
            float s = 0.f;
            #pragma unroll
            for (int mt = 0; mt < 2; ++mt) {
                f32x4 cc2 = {b3v[mt].x, b3v[mt].y, b3v[mt].z, b3v[mt].w};
                #pragma unroll
                for (int kc = 0; kc < 4; ++kc)
                    cc2 = MFMA16(t3[kc][mt], a3[u][kc], cc2);
                const float* wv = &w4v[mt].x;
                #pragma unroll
                for (int rr = 0; rr < 4; ++rr)
                    s = fmaf(fmaxf(cc2[rr], 0.f), wv[rr], s);
            }
            s += __shfl_xor(s, 16);   // sum quad partials
            s += __shfl_xor(s, 32);
            s += b4v;
            if (quad == 0)
                tab[a*NS + i0 + u*16 + col] = s;
        }
    }
}

// ---- field: dense 512-atom sweep, PREDICATED lookup + lerp, head ----
__global__ __launch_bounds__(256, 4) void field_kernel(
    const float* __restrict__ atom_pos,   // (512,3)
    const float* __restrict__ query_pos,  // (4096,3)
    const float* __restrict__ W5, const float* __restrict__ b5,  // (3,64),(64)
    const float* __restrict__ W6, const float* __restrict__ b6,  // (64,3),(3)
    const float* __restrict__ tab,        // (512, NS)
    float* __restrict__ out)              // (4096,3)
{
    __shared__ float px[512], py[512], pz[512];   // 6KB SoA, conflict-free

    const int tid  = threadIdx.x;
    const int wave = __builtin_amdgcn_readfirstlane(tid >> 6);
    const int lane = tid & 63;
    const int q    = blockIdx.x * 4 + wave;   // grid=1024 -> q < 4096

    #pragma unroll
    for (int i = tid; i < 512; i += 256) {
        px[i] = atom_pos[i*3+0];
        py[i] = atom_pos[i*3+1];
        pz[i] = atom_pos[i*3+2];
    }
    __syncthreads();

    const float qx = query_pos[q*3+0];
    const float qy = query_pos[q*3+1];
    const float qz = query_pos[q*3+2];

    float acc0 = 0.f, acc1 = 0.f, acc2 = 0.f;
    #pragma unroll
    for (int it = 0; it < 8; ++it) {
        const int a = it*64 + lane;
        const float rx = qx - px[a];
        const float ry = qy - py[a];
        const float rz = qz - pz[a];
        // EXACT reference dist sequence (mask boundary bitwise-stable)
        const float ex = __fadd_rn(rx, 1e-12f);
        const float ey = __fadd_rn(ry, 1e-12f);
        const float ez = __fadd_rn(rz, 1e-12f);
        const float dd = __fadd_rn(__fadd_rn(__fmul_rn(ex,ex), __fmul_rn(ey,ey)),
                                   __fmul_rn(ez,ez));
        const float dist = sqrtf(dd);
        const bool  in   = dist <= 6.0f;
        const float t  = __fmul_rn(dist, 85.166664f);   // (NS-1)/6
        int   i  = (int)t;
        i = i < (NS-2) ? i : (NS-2);
        const float frac = t - (float)i;
        // predicated gather: exec mask suppresses VMEM requests for the
        // ~2/3 out-of-range lanes (their wm is 0 regardless)
        float s0 = 0.f, s1 = 0.f;
        if (in) {
            const float* row = tab + a*NS;
            s0 = row[i];
            s1 = row[i+1];
        }
        const float sv = fmaf(frac, s1 - s0, s0);
        const float inv = __builtin_amdgcn_rcpf(dist + 1e-12f);
        const float wm  = in ? sv * inv : 0.f;
        acc0 = fmaf(wm, rx, acc0);
        acc1 = fmaf(wm, ry, acc1);
        acc2 = fmaf(wm, rz, acc2);
    }

    // ---- 64-lane butterfly (each atom counted exactly once) ----
    #pragma unroll
    for (int o = 1; o < 64; o <<= 1) {
        acc0 += __shfl_xor(acc0, o);
        acc1 += __shfl_xor(acc1, o);
        acc2 += __shfl_xor(acc2, o);
    }

    // ---- head: 3 -> 64 -> 3, per wave (lane = hidden unit) ----
    int hz = 0;
    asm volatile("" : "+v"(hz));   // keep head loads after the loop
    const float w5x = W5[hz + lane];
    const float w5y = W5[hz + 64 + lane];
    const float w5z = W5[hz + 128 + lane];
    const float b5v = b5[hz + lane];
    float th = fmaf(acc0, w5x, fmaf(acc1, w5y, fmaf(acc2, w5z, b5v)));
    th = fmaxf(th, 0.f);
    float o0 = th * W6[hz + lane*3+0];
    float o1 = th * W6[hz + lane*3+1];
    float o2 = th * W6[hz + lane*3+2];
    #pragma unroll
    for (int o = 1; o < 64; o <<= 1) {
        o0 += __shfl_xor(o0, o);
        o1 += __shfl_xor(o1, o);
        o2 += __shfl_xor(o2, o);
    }
    if (lane == 0) {
        out[q*3+0] = o0 + b6[0];
        out[q*3+1] = o1 + b6[1];
        out[q*3+2] = o2 + b6[2];
    }
}

extern "C" void kernel_launch(void* const* d_in, const int* in_sizes, int n_in,
                              void* d_out, int out_size, void* d_ws, size_t ws_size,
                              hipStream_t stream) {
    const float* atom_pos  = (const float*)d_in[0];
    const float* atom_feat = (const float*)d_in[1];
    const float* query_pos = (const float*)d_in[2];
    const float* W1 = (const float*)d_in[3];  const float* b1 = (const float*)d_in[4];
    const float* W2 = (const float*)d_in[5];  const float* b2 = (const float*)d_in[6];
    const float* W3 = (const float*)d_in[7];  const float* b3 = (const float*)d_in[8];
    const float* W4 = (const float*)d_in[9];  const float* b4 = (const float*)d_in[10];
    const float* W5 = (const float*)d_in[11]; const float* b5 = (const float*)d_in[12];
    const float* W6 = (const float*)d_in[13]; const float* b6 = (const float*)d_in[14];
    float* out = (float*)d_out;
    float* tab = (float*)d_ws;   // 512*NS*4 = 1MB table

    hipLaunchKernelGGL(tabgen_kernel, dim3(1024), dim3(256), 0, stream,
                       atom_feat, W1, b1, W2, b2, W3, b3, W4, b4, tab);
    hipLaunchKernelGGL(field_kernel, dim3(1024), dim3(256), 0, stream,
                       atom_pos, query_pos, W5, b5, W6, b6,
                       (const float*)tab, out);
}

// Round 9
// 96.037 us; speedup vs baseline: 1.0764x; 1.0280x over previous
//
#include <hip/hip_runtime.h>
#include <math.h>

// AtomQueryFieldNet: NQ=4096, NA=512, pair MLP 18->64->64->32->1, cutoff mask,
// per-query 3-vector reduction, 3->64->3 head.
//
// R23: NS=256 table — tabgen work halved.
//  - R22 post-mortem: predicated gather gained 1.6us as modeled. Kernel path
//    ~20us over the ~78.5us harness floor (= two 256MB poison fills).
//    Largest controllable item: tabgen's 512x512 MLP sample grid.
//  - NS 512 -> 256: lerp error x4 (max ~1.4e-3/pair, RMS ~5e-3 over ~180
//    in-range atoms) — still buried under the 0.0156 f16-MLP floor; threshold
//    is 0.0712. tabgen waves 4096 -> 2048 (grid 512, 2 blocks/CU, one round);
//    weight staging halves to 512x16KB. Table 512KB = L2-resident per XCD.
//  - Wave map: wc = bid*4+wave in [0,2048), atom = wc>>2, span (wc&3)*64,
//    2 chunks of 32 samples. d_i = i*6/255. Field scale 42.5 = 255/6 exact.
//  - Keeps R22: predicated table gather (exec-mask suppresses ~2/3 of VMEM
//    requests), fused in-block repack (f32->f16 cvt chain unchanged),
//    #pragma unroll 1 + opaque wb keeps frag ds_reads transient, EXACT
//    reference dist sequence (cutoff boundary bitwise-stable), K=16 MFMA
//    chaining identity, 3->64->3 head per wave.
//  - ws: [0, 512KB) scalar f32 table.

typedef _Float16 f16x4 __attribute__((ext_vector_type(4)));
typedef _Float16 f16x2 __attribute__((ext_vector_type(2)));
typedef float    f32x4 __attribute__((ext_vector_type(4)));

#define NS 256        // distance samples per atom over [0,6]

#define MFMA16(A,B,C) __builtin_amdgcn_mfma_f32_16x16x16f16(A,B,C,0,0,0)

__device__ __forceinline__ float exp2_fast(float x) {
    float r;
    asm("v_exp_f32 %0, %1" : "=v"(r) : "v"(x));
    return r;
}

__device__ __forceinline__ f16x4 relu_cvt(f32x4 c) {
    return f16x4{(_Float16)fmaxf(c[0],0.f), (_Float16)fmaxf(c[1],0.f),
                 (_Float16)fmaxf(c[2],0.f), (_Float16)fmaxf(c[3],0.f)};
}

// ---- tabgen: G_a(d_i), a in [0,512), i in [0,NS), d_i = i*6/255 ----
// Fused in-block repack: wlds frag layout (32 f16x4 frags x 64 lanes):
//   f 0..7  L1 (kc*4+mt, kc<2)   elem j: W1'[k=kc*16+quad*4+j][mt*16+col]
//   f 8..23 L2 (kc*4+mt, kc<4)           W2 [k][mt*16+col]
//   f 24..31 L3 (kc*2+mt, kc<4)          W3 [k][mt*16+col]
// W1' ROW-PERMUTED: k 0..15 = rbf rows (orig 2..17), k16=f0(row0),
// k17=f1(row1), k18=b1, k>=19 zero. biaslds[128] = {b2[64], b3[32], W4[32]}.
// Grid 512 x 256: wave wc = bid*4+wave owns atom wc>>2, samples
// [(wc&3)*64, +64) as 2 chunks of 32.
__global__ __launch_bounds__(256, 4) void tabgen_kernel(
    const float* __restrict__ atom_feat,  // (512,2)
    const float* __restrict__ W1, const float* __restrict__ b1,
    const float* __restrict__ W2, const float* __restrict__ b2,
    const float* __restrict__ W3, const float* __restrict__ b3,
    const float* __restrict__ W4, const float* __restrict__ b4,
    float* __restrict__ tab)              // (512, NS)
{
    __shared__ __align__(16) f16x4 wlds[2048];     // 16KB frags
    __shared__ __align__(16) float biaslds[128];   // 512B biases

    const int tid  = threadIdx.x;
    const int wave = __builtin_amdgcn_readfirstlane(tid >> 6);
    const int lane = tid & 63;
    const int col  = lane & 15;
    const int quad = lane >> 4;

    // ---- fused repack: global -> LDS (8 frag slots per thread) ----
    #pragma unroll
    for (int sidx = 0; sidx < 8; ++sidx) {
        const int s  = tid + sidx*256;     // slot = frag*64 + lane
        const int b  = s >> 6;
        const int sl = s & 63;
        const int scol = sl & 15, squad = sl >> 4;
        f16x4 v;
        #pragma unroll
        for (int j = 0; j < 4; ++j) {
            float x;
            if (b < 8) {
                const int kc = b >> 2, mt = b & 3;
                const int k = kc*16 + squad*4 + j;
                if (k < 16)       x = W1[(k+2)*64 + mt*16 + scol];  // rbf rows
                else if (k == 16) x = W1[        mt*16 + scol];     // f0
                else if (k == 17) x = W1[ 64   + mt*16 + scol];     // f1
                else if (k == 18) x = b1[        mt*16 + scol];     // bias slot
                else              x = 0.0f;
            } else if (b < 24) {
                const int idx = b - 8, kc = idx >> 2, mt = idx & 3;
                const int k = kc*16 + squad*4 + j;
                x = W2[k*64 + mt*16 + scol];
            } else {
                const int idx = b - 24, kc = idx >> 1, mt = idx & 1;
                const int k = kc*16 + squad*4 + j;
                x = W3[k*32 + mt*16 + scol];
            }
            v[j] = (_Float16)x;
        }
        wlds[s] = v;
    }
    if (tid < 128) {
        float x;
        if (tid < 64)       x = b2[tid];
        else if (tid < 96)  x = b3[tid - 64];
        else                x = W4[tid - 96];
        biaslds[tid] = x;
    }
    __syncthreads();

    const int wc     = blockIdx.x * 4 + wave;  // 0..2047
    const int a      = wc >> 2;                // atom (4 waves per atom)
    const int i0base = (wc & 3) * 64;          // 64-sample span, 2 chunks
    const float f0  = atom_feat[a*2+0];        // wave-uniform
    const float f1  = atom_feat[a*2+1];
    const float b4v = b4[0];

    // centers linspace(0,6,16): exp(-10 t^2) = 2^(-(s*t)^2),
    // s = sqrt(10*log2 e) = 3.7982831, step 0.4*s = 1.5193132.
    const float cbase = 1.5193132f * (float)(quad*4);

    #pragma unroll 1
    for (int cc = 0; cc < 2; ++cc) {
        const int i0 = i0base + cc*32;

        // opaque zero: keeps frag/bias ds_reads transient per chunk
        int wb = 0;
        asm volatile("" : "+v"(wb));
        const float4* bias4 = (const float4*)biaslds;

        f16x4 xa0[2], xa1[2];
        #pragma unroll
        for (int u = 0; u < 2; ++u) {
            const int   idx  = i0 + u*16 + col;
            const float dist = (float)idx * (6.0f/255.0f);
            const float base = __fmul_rn(dist, 3.7982831f) - cbase;
            #pragma unroll
            for (int j = 0; j < 4; ++j) {
                const float t = base - 1.5193132f * (float)j;
                xa0[u][j] = (_Float16)exp2_fast(t * -t);
            }
            const bool q0 = (quad == 0);
            xa1[u] = f16x4{q0 ? (_Float16)f0 : (_Float16)0.f,
                           q0 ? (_Float16)f1 : (_Float16)0.f,
                           (_Float16)(q0 ? 1.f : 0.f),
                           (_Float16)0.f};
        }

        // ---- L1 ----
        f16x4 t1[2][4];
        #pragma unroll
        for (int kc = 0; kc < 2; ++kc)
            #pragma unroll
            for (int mt = 0; mt < 4; ++mt)
                t1[kc][mt] = wlds[wb + (kc*4 + mt)*64 + lane];
        f16x4 a2[2][4];
        #pragma unroll
        for (int u = 0; u < 2; ++u)
            #pragma unroll
            for (int mt = 0; mt < 4; ++mt) {
                f32x4 cc2 = {0.f, 0.f, 0.f, 0.f};
                cc2 = MFMA16(t1[0][mt], xa0[u], cc2);
                cc2 = MFMA16(t1[1][mt], xa1[u], cc2);
                a2[u][mt] = relu_cvt(cc2);
            }

        // ---- L2 ----
        f16x4 t2[4][4];
        #pragma unroll
        for (int kc = 0; kc < 4; ++kc)
            #pragma unroll
            for (int mt = 0; mt < 4; ++mt)
                t2[kc][mt] = wlds[wb + (8 + kc*4 + mt)*64 + lane];
        float4 b2v[4];
        #pragma unroll
        for (int mt = 0; mt < 4; ++mt) b2v[mt] = bias4[wb + mt*4 + quad];
        f16x4 a3[2][4];
        #pragma unroll
        for (int u = 0; u < 2; ++u)
            #pragma unroll
            for (int mt = 0; mt < 4; ++mt) {
                f32x4 cc2 = {b2v[mt].x, b2v[mt].y, b2v[mt].z, b2v[mt].w};
                #pragma unroll
                for (int kc = 0; kc < 4; ++kc)
                    cc2 = MFMA16(t2[kc][mt], a2[u][kc], cc2);
                a3[u][mt] = relu_cvt(cc2);
            }

        // ---- L3 + L4 partial + quad-reduce -> store ----
        f16x4 t3[4][2];
        #pragma unroll
        for (int kc = 0; kc < 4; ++kc)
            #pragma unroll
            for (int mt = 0; mt < 2; ++mt)
                t3[kc][mt] = wlds[wb + (24 + kc*2 + mt)*64 + lane];
        float4 b3v[2], w4v[2];
        #pragma unroll
        for (int mt = 0; mt < 2; ++mt) {
            b3v[mt] = bias4[wb + 16 + mt*4 + quad];
            w4v[mt] = bias4[wb + 24 + mt*4 + quad];
        }
        #pragma unroll
        for (int u = 0; u < 2; ++u) {
            float s = 0.f;
            #pragma unroll
            for (int mt = 0; mt < 2; ++mt) {
                f32x4 cc2 = {b3v[mt].x, b3v[mt].y, b3v[mt].z, b3v[mt].w};
                #pragma unroll
                for (int kc = 0; kc < 4; ++kc)
                    cc2 = MFMA16(t3[kc][mt], a3[u][kc], cc2);
                const float* wv = &w4v[mt].x;
                #pragma unroll
                for (int rr = 0; rr < 4; ++rr)
                    s = fmaf(fmaxf(cc2[rr], 0.f), wv[rr], s);
            }
            s += __shfl_xor(s, 16);   // sum quad partials
            s += __shfl_xor(s, 32);
            s += b4v;
            if (quad == 0)
                tab[a*NS + i0 + u*16 + col] = s;
        }
    }
}

// ---- field: dense 512-atom sweep, PREDICATED lookup + lerp, head ----
__global__ __launch_bounds__(256, 4) void field_kernel(
    const float* __restrict__ atom_pos,   // (512,3)
    const float* __restrict__ query_pos,  // (4096,3)
    const float* __restrict__ W5, const float* __restrict__ b5,  // (3,64),(64)
    const float* __restrict__ W6, const float* __restrict__ b6,  // (64,3),(3)
    const float* __restrict__ tab,        // (512, NS)
    float* __restrict__ out)              // (4096,3)
{
    __shared__ float px[512], py[512], pz[512];   // 6KB SoA, conflict-free

    const int tid  = threadIdx.x;
    const int wave = __builtin_amdgcn_readfirstlane(tid >> 6);
    const int lane = tid & 63;
    const int q    = blockIdx.x * 4 + wave;   // grid=1024 -> q < 4096

    #pragma unroll
    for (int i = tid; i < 512; i += 256) {
        px[i] = atom_pos[i*3+0];
        py[i] = atom_pos[i*3+1];
        pz[i] = atom_pos[i*3+2];
    }
    __syncthreads();

    const float qx = query_pos[q*3+0];
    const float qy = query_pos[q*3+1];
    const float qz = query_pos[q*3+2];

    float acc0 = 0.f, acc1 = 0.f, acc2 = 0.f;
    #pragma unroll
    for (int it = 0; it < 8; ++it) {
        const int a = it*64 + lane;
        const float rx = qx - px[a];
        const float ry = qy - py[a];
        const float rz = qz - pz[a];
        // EXACT reference dist sequence (mask boundary bitwise-stable)
        const float ex = __fadd_rn(rx, 1e-12f);
        const float ey = __fadd_rn(ry, 1e-12f);
        const float ez = __fadd_rn(rz, 1e-12f);
        const float dd = __fadd_rn(__fadd_rn(__fmul_rn(ex,ex), __fmul_rn(ey,ey)),
                                   __fmul_rn(ez,ez));
        const float dist = sqrtf(dd);
        const bool  in   = dist <= 6.0f;
        const float t  = __fmul_rn(dist, 42.5f);   // (NS-1)/6 = 255/6, exact
        int   i  = (int)t;
        i = i < (NS-2) ? i : (NS-2);
        const float frac = t - (float)i;
        // predicated gather: exec mask suppresses VMEM requests for the
        // ~2/3 out-of-range lanes (their wm is 0 regardless)
        float s0 = 0.f, s1 = 0.f;
        if (in) {
            const float* row = tab + a*NS;
            s0 = row[i];
            s1 = row[i+1];
        }
        const float sv = fmaf(frac, s1 - s0, s0);
        const float inv = __builtin_amdgcn_rcpf(dist + 1e-12f);
        const float wm  = in ? sv * inv : 0.f;
        acc0 = fmaf(wm, rx, acc0);
        acc1 = fmaf(wm, ry, acc1);
        acc2 = fmaf(wm, rz, acc2);
    }

    // ---- 64-lane butterfly (each atom counted exactly once) ----
    #pragma unroll
    for (int o = 1; o < 64; o <<= 1) {
        acc0 += __shfl_xor(acc0, o);
        acc1 += __shfl_xor(acc1, o);
        acc2 += __shfl_xor(acc2, o);
    }

    // ---- head: 3 -> 64 -> 3, per wave (lane = hidden unit) ----
    int hz = 0;
    asm volatile("" : "+v"(hz));   // keep head loads after the loop
    const float w5x = W5[hz + lane];
    const float w5y = W5[hz + 64 + lane];
    const float w5z = W5[hz + 128 + lane];
    const float b5v = b5[hz + lane];
    float th = fmaf(acc0, w5x, fmaf(acc1, w5y, fmaf(acc2, w5z, b5v)));
    th = fmaxf(th, 0.f);
    float o0 = th * W6[hz + lane*3+0];
    float o1 = th * W6[hz + lane*3+1];
    float o2 = th * W6[hz + lane*3+2];
    #pragma unroll
    for (int o = 1; o < 64; o <<= 1) {
        o0 += __shfl_xor(o0, o);
        o1 += __shfl_xor(o1, o);
        o2 += __shfl_xor(o2, o);
    }
    if (lane == 0) {
        out[q*3+0] = o0 + b6[0];
        out[q*3+1] = o1 + b6[1];
        out[q*3+2] = o2 + b6[2];
    }
}

extern "C" void kernel_launch(void* const* d_in, const int* in_sizes, int n_in,
                              void* d_out, int out_size, void* d_ws, size_t ws_size,
                              hipStream_t stream) {
    const float* atom_pos  = (const float*)d_in[0];
    const float* atom_feat = (const float*)d_in[1];
    const float* query_pos = (const float*)d_in[2];
    const float* W1 = (const float*)d_in[3];  const float* b1 = (const float*)d_in[4];
    const float* W2 = (const float*)d_in[5];  const float* b2 = (const float*)d_in[6];
    const float* W3 = (const float*)d_in[7];  const float* b3 = (const float*)d_in[8];
    const float* W4 = (const float*)d_in[9];  const float* b4 = (const float*)d_in[10];
    const float* W5 = (const float*)d_in[11]; const float* b5 = (const float*)d_in[12];
    const float* W6 = (const float*)d_in[13]; const float* b6 = (const float*)d_in[14];
    float* out = (float*)d_out;
    float* tab = (float*)d_ws;   // 512*NS*4 = 512KB table

    hipLaunchKernelGGL(tabgen_kernel, dim3(512), dim3(256), 0, stream,
                       atom_feat, W1, b1, W2, b2, W3, b3, W4, b4, tab);
    hipLaunchKernelGGL(field_kernel, dim3(1024), dim3(256), 0, stream,
                       atom_pos, query_pos, W5, b5, W6, b6,
                       (const float*)tab, out);
}

// Round 10
// 94.995 us; speedup vs baseline: 1.0882x; 1.0110x over previous
//
#include <hip/hip_runtime.h>
#include <math.h>

// AtomQueryFieldNet: NQ=4096, NA=512, pair MLP 18->64->64->32->1, cutoff mask,
// per-query 3-vector reduction, 3->64->3 head.
//
// R24: NS=128 table — final tabgen halving.
//  - Evidence: NS 512->256 left absmax EXACTLY at the 0.015625 f16-output
//    floor -> interp error at NS=256 is far below the floor. One more halving
//    adds worst-case ~8e-3 (threshold 0.0712, 3x headroom). NS=64 would be
//    the reckless x16 step; not taken.
//  - tabgen waves 2048 -> 1024 (grid 256, 1 block/CU, one round); weight
//    staging 256x16KB = 4MB. Wave map: wc in [0,1024), atom = wc>>1, span
//    (wc&1)*64 as 2 chunks of 32. d_i = i*6/127. Table 256KB, L2-resident.
//  - Field: scale 127/6 = 21.166666, clamp i<=126 (d=6 lands i=126, frac->1).
//  - Keeps R22/R23: predicated table gather (exec-mask kills ~2/3 of VMEM
//    requests), fused in-block repack (f32->f16 cvt chain unchanged),
//    #pragma unroll 1 + opaque wb keeps frag ds_reads transient, EXACT
//    reference dist sequence (cutoff boundary bitwise-stable), K=16 MFMA
//    chaining identity, 3->64->3 head per wave.
//  - Structure locked: 2 dispatches (cooperative launch fails graph capture,
//    R21; semaphore single-dispatch risks scheduling deadlock). Harness floor
//    ~78.5us = two 256MB poison fills, not kernel-controllable.
//  - ws: [0, 256KB) scalar f32 table.

typedef _Float16 f16x4 __attribute__((ext_vector_type(4)));
typedef _Float16 f16x2 __attribute__((ext_vector_type(2)));
typedef float    f32x4 __attribute__((ext_vector_type(4)));

#define NS 128        // distance samples per atom over [0,6]

#define MFMA16(A,B,C) __builtin_amdgcn_mfma_f32_16x16x16f16(A,B,C,0,0,0)

__device__ __forceinline__ float exp2_fast(float x) {
    float r;
    asm("v_exp_f32 %0, %1" : "=v"(r) : "v"(x));
    return r;
}

__device__ __forceinline__ f16x4 relu_cvt(f32x4 c) {
    return f16x4{(_Float16)fmaxf(c[0],0.f), (_Float16)fmaxf(c[1],0.f),
                 (_Float16)fmaxf(c[2],0.f), (_Float16)fmaxf(c[3],0.f)};
}

// ---- tabgen: G_a(d_i), a in [0,512), i in [0,NS), d_i = i*6/127 ----
// Fused in-block repack: wlds frag layout (32 f16x4 frags x 64 lanes):
//   f 0..7  L1 (kc*4+mt, kc<2)   elem j: W1'[k=kc*16+quad*4+j][mt*16+col]
//   f 8..23 L2 (kc*4+mt, kc<4)           W2 [k][mt*16+col]
//   f 24..31 L3 (kc*2+mt, kc<4)          W3 [k][mt*16+col]
// W1' ROW-PERMUTED: k 0..15 = rbf rows (orig 2..17), k16=f0(row0),
// k17=f1(row1), k18=b1, k>=19 zero. biaslds[128] = {b2[64], b3[32], W4[32]}.
// Grid 256 x 256: wave wc = bid*4+wave owns atom wc>>1, samples
// [(wc&1)*64, +64) as 2 chunks of 32.
__global__ __launch_bounds__(256, 4) void tabgen_kernel(
    const float* __restrict__ atom_feat,  // (512,2)
    const float* __restrict__ W1, const float* __restrict__ b1,
    const float* __restrict__ W2, const float* __restrict__ b2,
    const float* __restrict__ W3, const float* __restrict__ b3,
    const float* __restrict__ W4, const float* __restrict__ b4,
    float* __restrict__ tab)              // (512, NS)
{
    __shared__ __align__(16) f16x4 wlds[2048];     // 16KB frags
    __shared__ __align__(16) float biaslds[128];   // 512B biases

    const int tid  = threadIdx.x;
    const int wave = __builtin_amdgcn_readfirstlane(tid >> 6);
    const int lane = tid & 63;
    const int col  = lane & 15;
    const int quad = lane >> 4;

    // ---- fused repack: global -> LDS (8 frag slots per thread) ----
    #pragma unroll
    for (int sidx = 0; sidx < 8; ++sidx) {
        const int s  = tid + sidx*256;     // slot = frag*64 + lane
        const int b  = s >> 6;
        const int sl = s & 63;
        const int scol = sl & 15, squad = sl >> 4;
        f16x4 v;
        #pragma unroll
        for (int j = 0; j < 4; ++j) {
            float x;
            if (b < 8) {
                const int kc = b >> 2, mt = b & 3;
                const int k = kc*16 + squad*4 + j;
                if (k < 16)       x = W1[(k+2)*64 + mt*16 + scol];  // rbf rows
                else if (k == 16) x = W1[        mt*16 + scol];     // f0
                else if (k == 17) x = W1[ 64   + mt*16 + scol];     // f1
                else if (k == 18) x = b1[        mt*16 + scol];     // bias slot
                else              x = 0.0f;
            } else if (b < 24) {
                const int idx = b - 8, kc = idx >> 2, mt = idx & 3;
                const int k = kc*16 + squad*4 + j;
                x = W2[k*64 + mt*16 + scol];
            } else {
                const int idx = b - 24, kc = idx >> 1, mt = idx & 1;
                const int k = kc*16 + squad*4 + j;
                x = W3[k*32 + mt*16 + scol];
            }
            v[j] = (_Float16)x;
        }
        wlds[s] = v;
    }
    if (tid < 128) {
        float x;
        if (tid < 64)       x = b2[tid];
        else if (tid < 96)  x = b3[tid - 64];
        else                x = W4[tid - 96];
        biaslds[tid] = x;
    }
    __syncthreads();

    const int wc     = blockIdx.x * 4 + wave;  // 0..1023
    const int a      = wc >> 1;                // atom (2 waves per atom)
    const int i0base = (wc & 1) * 64;          // 64-sample span, 2 chunks
    const float f0  = atom_feat[a*2+0];        // wave-uniform
    const float f1  = atom_feat[a*2+1];
    const float b4v = b4[0];

    // centers linspace(0,6,16): exp(-10 t^2) = 2^(-(s*t)^2),
    // s = sqrt(10*log2 e) = 3.7982831, step 0.4*s = 1.5193132.
    const float cbase = 1.5193132f * (float)(quad*4);

    #pragma unroll 1
    for (int cc = 0; cc < 2; ++cc) {
        const int i0 = i0base + cc*32;

        // opaque zero: keeps frag/bias ds_reads transient per chunk
        int wb = 0;
        asm volatile("" : "+v"(wb));
        const float4* bias4 = (const float4*)biaslds;

        f16x4 xa0[2], xa1[2];
        #pragma unroll
        for (int u = 0; u < 2; ++u) {
            const int   idx  = i0 + u*16 + col;
            const float dist = (float)idx * (6.0f/127.0f);
            const float base = __fmul_rn(dist, 3.7982831f) - cbase;
            #pragma unroll
            for (int j = 0; j < 4; ++j) {
                const float t = base - 1.5193132f * (float)j;
                xa0[u][j] = (_Float16)exp2_fast(t * -t);
            }
            const bool q0 = (quad == 0);
            xa1[u] = f16x4{q0 ? (_Float16)f0 : (_Float16)0.f,
                           q0 ? (_Float16)f1 : (_Float16)0.f,
                           (_Float16)(q0 ? 1.f : 0.f),
                           (_Float16)0.f};
        }

        // ---- L1 ----
        f16x4 t1[2][4];
        #pragma unroll
        for (int kc = 0; kc < 2; ++kc)
            #pragma unroll
            for (int mt = 0; mt < 4; ++mt)
                t1[kc][mt] = wlds[wb + (kc*4 + mt)*64 + lane];
        f16x4 a2[2][4];
        #pragma unroll
        for (int u = 0; u < 2; ++u)
            #pragma unroll
            for (int mt = 0; mt < 4; ++mt) {
                f32x4 cc2 = {0.f, 0.f, 0.f, 0.f};
                cc2 = MFMA16(t1[0][mt], xa0[u], cc2);
                cc2 = MFMA16(t1[1][mt], xa1[u], cc2);
                a2[u][mt] = relu_cvt(cc2);
            }

        // ---- L2 ----
        f16x4 t2[4][4];
        #pragma unroll
        for (int kc = 0; kc < 4; ++kc)
            #pragma unroll
            for (int mt = 0; mt < 4; ++mt)
                t2[kc][mt] = wlds[wb + (8 + kc*4 + mt)*64 + lane];
        float4 b2v[4];
        #pragma unroll
        for (int mt = 0; mt < 4; ++mt) b2v[mt] = bias4[wb + mt*4 + quad];
        f16x4 a3[2][4];
        #pragma unroll
        for (int u = 0; u < 2; ++u)
            #pragma unroll
            for (int mt = 0; mt < 4; ++mt) {
                f32x4 cc2 = {b2v[mt].x, b2v[mt].y, b2v[mt].z, b2v[mt].w};
                #pragma unroll
                for (int kc = 0; kc < 4; ++kc)
                    cc2 = MFMA16(t2[kc][mt], a2[u][kc], cc2);
                a3[u][mt] = relu_cvt(cc2);
            }

        // ---- L3 + L4 partial + quad-reduce -> store ----
        f16x4 t3[4][2];
        #pragma unroll
        for (int kc = 0; kc < 4; ++kc)
            #pragma unroll
            for (int mt = 0; mt < 2; ++mt)
                t3[kc][mt] = wlds[wb + (24 + kc*2 + mt)*64 + lane];
        float4 b3v[2], w4v[2];
        #pragma unroll
        for (int mt = 0; mt < 2; ++mt) {
            b3v[mt] = bias4[wb + 16 + mt*4 + quad];
            w4v[mt] = bias4[wb + 24 + mt*4 + quad];
        }
        #pragma unroll
        for (int u = 0; u < 2; ++u) {
            float s = 0.f;
            #pragma unroll
            for (int mt = 0; mt < 2; ++mt) {
                f32x4 cc2 = {b3v[mt].x, b3v[mt].y, b3v[mt].z, b3v[mt].w};
                #pragma unroll
                for (int kc = 0; kc < 4; ++kc)
                    cc2 = MFMA16(t3[kc][mt], a3[u][kc], cc2);
                const float* wv = &w4v[mt].x;
                #pragma unroll
                for (int rr = 0; rr < 4; ++rr)
                    s = fmaf(fmaxf(cc2[rr], 0.f), wv[rr], s);
            }
            s += __shfl_xor(s, 16);   // sum quad partials
            s += __shfl_xor(s, 32);
            s += b4v;
            if (quad == 0)
                tab[a*NS + i0 + u*16 + col] = s;
        }
    }
}

// ---- field: dense 512-atom sweep, PREDICATED lookup + lerp, head ----
__global__ __launch_bounds__(256, 4) void field_kernel(
    const float* __restrict__ atom_pos,   // (512,3)
    const float* __restrict__ query_pos,  // (4096,3)
    const float* __restrict__ W5, const float* __restrict__ b5,  // (3,64),(64)
    const float* __restrict__ W6, const float* __restrict__ b6,  // (64,3),(3)
    const float* __restrict__ tab,        // (512, NS)
    float* __restrict__ out)              // (4096,3)
{
    __shared__ float px[512], py[512], pz[512];   // 6KB SoA, conflict-free

    const int tid  = threadIdx.x;
    const int wave = __builtin_amdgcn_readfirstlane(tid >> 6);
    const int lane = tid & 63;
    const int q    = blockIdx.x * 4 + wave;   // grid=1024 -> q < 4096

    #pragma unroll
    for (int i = tid; i < 512; i += 256) {
        px[i] = atom_pos[i*3+0];
        py[i] = atom_pos[i*3+1];
        pz[i] = atom_pos[i*3+2];
    }
    __syncthreads();

    const float qx = query_pos[q*3+0];
    const float qy = query_pos[q*3+1];
    const float qz = query_pos[q*3+2];

    float acc0 = 0.f, acc1 = 0.f, acc2 = 0.f;
    #pragma unroll
    for (int it = 0; it < 8; ++it) {
        const int a = it*64 + lane;
        const float rx = qx - px[a];
        const float ry = qy - py[a];
        const float rz = qz - pz[a];
        // EXACT reference dist sequence (mask boundary bitwise-stable)
        const float ex = __fadd_rn(rx, 1e-12f);
        const float ey = __fadd_rn(ry, 1e-12f);
        const float ez = __fadd_rn(rz, 1e-12f);
        const float dd = __fadd_rn(__fadd_rn(__fmul_rn(ex,ex), __fmul_rn(ey,ey)),
                                   __fmul_rn(ez,ez));
        const float dist = sqrtf(dd);
        const bool  in   = dist <= 6.0f;
        const float t  = __fmul_rn(dist, 21.166666f);   // (NS-1)/6 = 127/6
        int   i  = (int)t;
        i = i < (NS-2) ? i : (NS-2);
        const float frac = t - (float)i;
        // predicated gather: exec mask suppresses VMEM requests for the
        // ~2/3 out-of-range lanes (their wm is 0 regardless)
        float s0 = 0.f, s1 = 0.f;
        if (in) {
            const float* row = tab + a*NS;
            s0 = row[i];
            s1 = row[i+1];
        }
        const float sv = fmaf(frac, s1 - s0, s0);
        const float inv = __builtin_amdgcn_rcpf(dist + 1e-12f);
        const float wm  = in ? sv * inv : 0.f;
        acc0 = fmaf(wm, rx, acc0);
        acc1 = fmaf(wm, ry, acc1);
        acc2 = fmaf(wm, rz, acc2);
    }

    // ---- 64-lane butterfly (each atom counted exactly once) ----
    #pragma unroll
    for (int o = 1; o < 64; o <<= 1) {
        acc0 += __shfl_xor(acc0, o);
        acc1 += __shfl_xor(acc1, o);
        acc2 += __shfl_xor(acc2, o);
    }

    // ---- head: 3 -> 64 -> 3, per wave (lane = hidden unit) ----
    int hz = 0;
    asm volatile("" : "+v"(hz));   // keep head loads after the loop
    const float w5x = W5[hz + lane];
    const float w5y = W5[hz + 64 + lane];
    const float w5z = W5[hz + 128 + lane];
    const float b5v = b5[hz + lane];
    float th = fmaf(acc0, w5x, fmaf(acc1, w5y, fmaf(acc2, w5z, b5v)));
    th = fmaxf(th, 0.f);
    float o0 = th * W6[hz + lane*3+0];
    float o1 = th * W6[hz + lane*3+1];
    float o2 = th * W6[hz + lane*3+2];
    #pragma unroll
    for (int o = 1; o < 64; o <<= 1) {
        o0 += __shfl_xor(o0, o);
        o1 += __shfl_xor(o1, o);
        o2 += __shfl_xor(o2, o);
    }
    if (lane == 0) {
        out[q*3+0] = o0 + b6[0];
        out[q*3+1] = o1 + b6[1];
        out[q*3+2] = o2 + b6[2];
    }
}

extern "C" void kernel_launch(void* const* d_in, const int* in_sizes, int n_in,
                              void* d_out, int out_size, void* d_ws, size_t ws_size,
                              hipStream_t stream) {
    const float* atom_pos  = (const float*)d_in[0];
    const float* atom_feat = (const float*)d_in[1];
    const float* query_pos = (const float*)d_in[2];
    const float* W1 = (const float*)d_in[3];  const float* b1 = (const float*)d_in[4];
    const float* W2 = (const float*)d_in[5];  const float* b2 = (const float*)d_in[6];
    const float* W3 = (const float*)d_in[7];  const float* b3 = (const float*)d_in[8];
    const float* W4 = (const float*)d_in[9];  const float* b4 = (const float*)d_in[10];
    const float* W5 = (const float*)d_in[11]; const float* b5 = (const float*)d_in[12];
    const float* W6 = (const float*)d_in[13]; const float* b6 = (const float*)d_in[14];
    float* out = (float*)d_out;
    float* tab = (float*)d_ws;   // 512*NS*4 = 256KB table

    hipLaunchKernelGGL(tabgen_kernel, dim3(256), dim3(256), 0, stream,
                       atom_feat, W1, b1, W2, b2, W3, b3, W4, b4, tab);
    hipLaunchKernelGGL(field_kernel, dim3(1024), dim3(256), 0, stream,
                       atom_pos, query_pos, W5, b5, W6, b6,
                       (const float*)tab, out);
}